// Round 7
// baseline (210.906 us; speedup 1.0000x reference)
//
#include <hip/hip_runtime.h>
#include <math.h>

#define N_NODES 200000
#define NF 128
#define NT 32
#define NS 32
#define NG 128
#define ATILE 256       // nodes per block (4 subtiles of 64)
#define NTILES 8        // max 256-node tiles per graph: 2048 = mean 1562 + 12 sigma
#define VSTRIDE 136     // v LDS row stride in shorts: 272 B, 16B-aligned, 2-way banks (free)
#define HPAD 33         // corr stride; (t*33+s)%32 = (t+s)%32 decorrelates banks

typedef short bf16x8 __attribute__((ext_vector_type(8)));
typedef float floatx4 __attribute__((ext_vector_type(4)));

__device__ __forceinline__ float rcp_fast(float x) { return __builtin_amdgcn_rcpf(x); }

// split fp32 into bf16 hi + bf16 lo (RTN both): f ~= hi + lo to ~2^-17 rel (proven path)
__device__ __forceinline__ void split_bf16(float f, unsigned short& h, unsigned short& l) {
    unsigned u  = __float_as_uint(f);
    unsigned r  = u + 0x7FFFu + ((u >> 16) & 1u);
    unsigned hb = r & 0xFFFF0000u;
    h = (unsigned short)(hb >> 16);
    float rem = f - __uint_as_float(hb);
    unsigned u2 = __float_as_uint(rem);
    unsigned r2 = u2 + 0x7FFFu + ((u2 >> 16) & 1u);
    l = (unsigned short)(r2 >> 16);
}

__device__ __forceinline__ void split8(float4 a, float4 b, bf16x8& h8, bf16x8& l8) {
    unsigned short h[8], l[8];
    split_bf16(a.x, h[0], l[0]); split_bf16(a.y, h[1], l[1]);
    split_bf16(a.z, h[2], l[2]); split_bf16(a.w, h[3], l[3]);
    split_bf16(b.x, h[4], l[4]); split_bf16(b.y, h[5], l[5]);
    split_bf16(b.z, h[6], l[6]); split_bf16(b.w, h[7], l[7]);
    h8 = (bf16x8){(short)h[0],(short)h[1],(short)h[2],(short)h[3],
                  (short)h[4],(short)h[5],(short)h[6],(short)h[7]};
    l8 = (bf16x8){(short)l[0],(short)l[1],(short)l[2],(short)l[3],
                  (short)l[4],(short)l[5],(short)l[6],(short)l[7]};
}

// deposit sigmoid differences at bins s0..s0+2 (window +-1.0 bin; boundary sigmoid 8.2e-4,
// per-cell accumulated error < 0.01 vs tolerance 4.0); inclusive scan reconstructs sigmoid
__device__ __forceinline__ void deposit(float* corr, int b, float z, float Lw, float C1) {
    float s0f = ceilf(z - 1.0f);                         // s0 in [-1, 31]
    int   s0  = (int)s0f;
    float e0  = __builtin_amdgcn_exp2f(Lw * (z - s0f));  // z-s0 in (0,1] -> e0 in (1, 1210]
    float e1  = e0 * C1;
    float f0  = rcp_fast(1.0f + e0);
    float f1  = rcp_fast(1.0f + e1);
    atomicAdd(&corr[b + max(s0, 0)], f0);
    int sB = s0 + 1; if (sB < 32) atomicAdd(&corr[b + sB], f1 - f0);   // sB >= 0 always
    int sC = s0 + 2; if (sC < 32) atomicAdd(&corr[b + sC], 1.0f - f1);
}

// ---- kernel A: graph start offsets from sorted batch (starts[g] = lower_bound(batch, g)) ----
__global__ __launch_bounds__(256)
void graph_starts(const int* __restrict__ batch, int* __restrict__ starts) {
    int i = blockIdx.x * 256 + threadIdx.x;
    if (i >= N_NODES) return;
    int b    = batch[i];
    int prev = (i == 0) ? -1 : batch[i - 1];
    for (int g = prev + 1; g <= b; ++g) starts[g] = i;      // unique writer per g
    if (i == N_NODES - 1)
        for (int g = b + 1; g <= NG; ++g) starts[g] = N_NODES;
}

// ---- main kernel: one graph-aligned 256-node tile per block, 4 barrier-free subtiles ----
__global__ __launch_bounds__(256, 7)   // 21.6 KB LDS -> 7 blocks/CU
void ect_tile(const float* __restrict__ x,
              const float* __restrict__ v,
              const int* __restrict__ starts,
              float* __restrict__ partials,   // [NG*NTILES][1024]
              float* __restrict__ out,        // fallback target (atomics) when !use_ws
              int use_ws)
{
    __shared__ __align__(16) unsigned short vh[NT * VSTRIDE];  // 8704 B
    __shared__ __align__(16) unsigned short vl[NT * VSTRIDE];  // 8704 B
    __shared__ float corr[NT * HPAD];                          // 4224 B

    const int tid  = threadIdx.x;
    const int t    = blockIdx.x;    // tile within graph
    const int g    = blockIdx.y;    // graph
    const int w    = tid >> 6;
    const int lane = tid & 63;
    const int mrow = lane & 15;
    const int quad = lane >> 4;

    const int start = starts[g];
    const int count = starts[g + 1] - start;
    const int slot  = g * NTILES + t;

    if (t * ATILE >= count) {                    // idle tile: zero-fill ws slot
        if (use_ws) {
            float4 z4 = {0.f, 0.f, 0.f, 0.f};
            *(float4*)&partials[(size_t)slot * 1024 + tid * 4] = z4;
        }
        return;                                  // block-uniform, before any barrier
    }
    const int base   = start + t * ATILE;
    const int nvalid = min(ATILE, count - t * ATILE);  // in [1, 256]
    const int nsub   = (nvalid + 63) >> 6;             // subtiles of 64 rows

    // ---- stage v -> bf16 hi/lo in LDS + clear corr (once per 256 nodes) ----
    #pragma unroll
    for (int j = 0; j < 4; ++j) {
        int idx4 = j * 256 + tid;
        int row  = idx4 >> 5;
        int f4   = idx4 & 31;
        float4 val = *(const float4*)&v[(size_t)row * NF + f4 * 4];
        unsigned short h0,h1,h2,h3,l0,l1,l2,l3;
        split_bf16(val.x, h0, l0); split_bf16(val.y, h1, l1);
        split_bf16(val.z, h2, l2); split_bf16(val.w, h3, l3);
        uint2 hh, ll;
        hh.x = (unsigned)h0 | ((unsigned)h1 << 16); hh.y = (unsigned)h2 | ((unsigned)h3 << 16);
        ll.x = (unsigned)l0 | ((unsigned)l1 << 16); ll.y = (unsigned)l2 | ((unsigned)l3 << 16);
        *(uint2*)&vh[row * VSTRIDE + f4 * 4] = hh;
        *(uint2*)&vl[row * VSTRIDE + f4 * 4] = ll;
    }
    for (int i = tid; i < NT * HPAD; i += 256) corr[i] = 0.0f;
    __syncthreads();   // vh/vl + corr ready

    const float inv_dlin = 14.090909090909092f; // 31/2.2
    const float Lw       = 10.23848093f;        // SCALE * dlin * log2(e)
    const float dlin     = 2.2f / 31.0f;
    const float L        = 144.26950408889634f; // SCALE * log2(e)
    const float C1       = 8.2777115e-04f;      // 2^-Lw = exp(-SCALE*dlin)

    const int b0base = mrow * VSTRIDE + quad * 8;
    const int b1base = (16 + mrow) * VSTRIDE + quad * 8;
    const int c0base = mrow * HPAD;
    const int c1base = (16 + mrow) * HPAD;

    float c0 = 0.f, c1 = 0.f;   // saturated-low counts, accumulated across subtiles

    for (int k = 0; k < nsub; ++k) {   // NO barriers in this loop: deposits are LDS atomics
        // A fragments straight from global (invalid tail rows clamped; filtered in sweep)
        const int gi = min(base + k * 64 + w * 16 + mrow, N_NODES - 1);
        const float* __restrict__ xrow = x + (size_t)gi * NF + quad * 8;
        bf16x8 ah[4], al[4];
        #pragma unroll
        for (int slice = 0; slice < 4; ++slice) {
            float4 a0 = *(const float4*)&xrow[slice * 32];
            float4 a1 = *(const float4*)&xrow[slice * 32 + 4];
            split8(a0, a1, ah[slice], al[slice]);
        }

        floatx4 acc0 = {0.f, 0.f, 0.f, 0.f};   // thetas 0..15  (col = mrow)
        floatx4 acc1 = {0.f, 0.f, 0.f, 0.f};   // thetas 16..31
        #pragma unroll
        for (int slice = 0; slice < 4; ++slice) {
            bf16x8 bh0 = *(bf16x8*)&vh[b0base + slice * 32];
            bf16x8 bl0 = *(bf16x8*)&vl[b0base + slice * 32];
            bf16x8 bh1 = *(bf16x8*)&vh[b1base + slice * 32];
            bf16x8 bl1 = *(bf16x8*)&vl[b1base + slice * 32];
            acc0 = __builtin_amdgcn_mfma_f32_16x16x32_bf16(ah[slice], bh0, acc0, 0, 0, 0);
            acc0 = __builtin_amdgcn_mfma_f32_16x16x32_bf16(ah[slice], bl0, acc0, 0, 0, 0);
            acc0 = __builtin_amdgcn_mfma_f32_16x16x32_bf16(al[slice], bh0, acc0, 0, 0, 0);
            acc1 = __builtin_amdgcn_mfma_f32_16x16x32_bf16(ah[slice], bh1, acc1, 0, 0, 0);
            acc1 = __builtin_amdgcn_mfma_f32_16x16x32_bf16(ah[slice], bl1, acc1, 0, 0, 0);
            acc1 = __builtin_amdgcn_mfma_f32_16x16x32_bf16(al[slice], bh1, acc1, 0, 0, 0);
        }
        // C/D layout: col = lane&15 (theta), row = quad*4 + reg (node-in-16-tile)

        // dense sweep: 8 positions/thread, difference deposits
        const int nloc = k * 64 + w * 16 + quad * 4;
        #pragma unroll
        for (int reg = 0; reg < 4; ++reg) {
            if (nloc + reg < nvalid) {
                {   // theta = mrow
                    float z = fmaf(acc0[reg], inv_dlin, 15.5f);   // (h + 1.1)/dlin
                    if (z <= -1.0f)      c0 += 1.0f;
                    else if (z < 32.0f)  deposit(corr, c0base, z, Lw, C1);
                }
                {   // theta = 16 + mrow
                    float z = fmaf(acc1[reg], inv_dlin, 15.5f);
                    if (z <= -1.0f)      c1 += 1.0f;
                    else if (z < 32.0f)  deposit(corr, c1base, z, Lw, C1);
                }
            }
        }
    }
    if (c0 != 0.f) atomicAdd(&corr[c0base], c0);
    if (c1 != 0.f) atomicAdd(&corr[c1base], c1);
    __syncthreads();

    // ---- inclusive prefix-scan each theta row in place -> sigmoid partial sums ----
    {
        const int grp = tid >> 5;   // 8 groups x 32 lanes; group handles rows grp+8i
        const int sc  = tid & 31;
        for (int row = grp; row < NT; row += 8) {
            float val = corr[row * HPAD + sc];
            #pragma unroll
            for (int d = 1; d < 32; d <<= 1) {
                float nbr = __shfl_up(val, d, 32);
                if (sc >= d) val += nbr;
            }
            corr[row * HPAD + sc] = val;
        }
    }
    __syncthreads();

    // ---- flush: thread owns out-flat indices 4*tid..4*tid+3 (s = tid>>3, ft = (tid&7)*4+j) ----
    const float cnt  = (float)nvalid;
    const int   s    = tid >> 3;
    const int   ft0  = (tid & 7) * 4;
    const float lin_s = -1.1f + (float)s * dlin;
    const float cs    = rcp_fast(1.0f + __builtin_amdgcn_exp2f(L * (1.1f - lin_s)));
    float4 r;
    r.x = corr[(ft0 + 0) * HPAD + s] - cnt * cs;
    r.y = corr[(ft0 + 1) * HPAD + s] - cnt * cs;
    r.z = corr[(ft0 + 2) * HPAD + s] - cnt * cs;
    r.w = corr[(ft0 + 3) * HPAD + s] - cnt * cs;
    if (use_ws) {
        *(float4*)&partials[(size_t)slot * 1024 + tid * 4] = r;   // private slot, coalesced
    } else {
        float* o = out + (size_t)g * (NS * NT) + tid * 4;
        atomicAdd(&o[0], r.x); atomicAdd(&o[1], r.y);
        atomicAdd(&o[2], r.z); atomicAdd(&o[3], r.w);
    }
}

// ---- reduce: out[g][:] = sum over tiles of partials[g][t][:] ----
__global__ __launch_bounds__(256)
void reduce_partials(const float* __restrict__ partials, float* __restrict__ out) {
    const int g   = blockIdx.x;
    const int tid = threadIdx.x;
    const float4* p4 = (const float4*)partials;
    float4 acc = {0.f, 0.f, 0.f, 0.f};
    #pragma unroll
    for (int t = 0; t < NTILES; ++t) {
        float4 v = p4[(size_t)(g * NTILES + t) * 256 + tid];
        acc.x += v.x; acc.y += v.y; acc.z += v.z; acc.w += v.w;
    }
    ((float4*)out)[(size_t)g * 256 + tid] = acc;
}

extern "C" void kernel_launch(void* const* d_in, const int* in_sizes, int n_in,
                              void* d_out, int out_size, void* d_ws, size_t ws_size,
                              hipStream_t stream) {
    const float* x     = (const float*)d_in[0];
    const int*   batch = (const int*)d_in[1];
    const float* v     = (const float*)d_in[3];
    float*       out   = (float*)d_out;

    int*   starts   = (int*)d_ws;                                // 516 B used
    float* partials = (float*)((char*)d_ws + 1024);
    const size_t need = 1024 + (size_t)NG * NTILES * 1024 * sizeof(float);  // ~4.2 MB
    const int use_ws  = (ws_size >= need) ? 1 : 0;

    hipMemsetAsync(d_out, 0, (size_t)out_size * sizeof(float), stream);
    graph_starts<<<dim3((N_NODES + 255) / 256), dim3(256), 0, stream>>>(batch, starts);
    ect_tile<<<dim3(NTILES, NG), dim3(256), 0, stream>>>(x, v, starts, partials, out, use_ws);
    if (use_ws)
        reduce_partials<<<dim3(NG), dim3(256), 0, stream>>>(partials, out);
}

// Round 8
// 173.566 us; speedup vs baseline: 1.2151x; 1.2151x over previous
//
#include <hip/hip_runtime.h>
#include <hip/hip_bf16.h>
#include <math.h>

#define N_NODES 200000
#define NF 128
#define NT 32
#define NS 32
#define NG 128
#define ATILE 64        // nodes per block; best measured config (R6)
#define NTILES 30       // max 64-node tiles per graph: mean 24.4, +9 sigma
#define VSTRIDE 136     // v LDS row stride in shorts: 272 B, 16B-aligned, 2-way banks (free)
#define HPAD 33         // corr stride; (t*33+s)%32 = (t+s)%32 decorrelates banks

typedef short bf16x8 __attribute__((ext_vector_type(8)));
typedef float floatx4 __attribute__((ext_vector_type(4)));

__device__ __forceinline__ float rcp_fast(float x) { return __builtin_amdgcn_rcpf(x); }

// bf16 split via HW convert: h = RNE bf16(f), l = RNE bf16(f - h).
// Self-correcting: total error = rounding error of l (~2^-17 rel), independent of h's mode.
__device__ __forceinline__ unsigned short bf16_bits(float f) {
    __hip_bfloat16 h = __float2bfloat16(f);
    unsigned short u; __builtin_memcpy(&u, &h, 2); return u;
}
__device__ __forceinline__ float bf16_val(unsigned short u) {
    unsigned v = (unsigned)u << 16; float f; __builtin_memcpy(&f, &v, 4); return f;
}
__device__ __forceinline__ void split1(float f, unsigned short& h, unsigned short& l) {
    h = bf16_bits(f);
    l = bf16_bits(f - bf16_val(h));
}

__device__ __forceinline__ void split8(float4 a, float4 b, bf16x8& h8, bf16x8& l8) {
    unsigned short h[8], l[8];
    split1(a.x, h[0], l[0]); split1(a.y, h[1], l[1]);
    split1(a.z, h[2], l[2]); split1(a.w, h[3], l[3]);
    split1(b.x, h[4], l[4]); split1(b.y, h[5], l[5]);
    split1(b.z, h[6], l[6]); split1(b.w, h[7], l[7]);
    h8 = (bf16x8){(short)h[0],(short)h[1],(short)h[2],(short)h[3],
                  (short)h[4],(short)h[5],(short)h[6],(short)h[7]};
    l8 = (bf16x8){(short)l[0],(short)l[1],(short)l[2],(short)l[3],
                  (short)l[4],(short)l[5],(short)l[6],(short)l[7]};
}

// deposit sigmoid differences at bins s0..s0+2 (window +-1.0 bin; boundary sigmoid 8.2e-4,
// harness-proven round 7); inclusive scan reconstructs sigmoid
__device__ __forceinline__ void deposit(float* corr, int b, float z, float Lw, float C1) {
    float s0f = ceilf(z - 1.0f);                         // s0 in [-1, 31]
    int   s0  = (int)s0f;
    float e0  = __builtin_amdgcn_exp2f(Lw * (z - s0f));  // z-s0 in (0,1]
    float e1  = e0 * C1;
    float f0  = rcp_fast(1.0f + e0);
    float f1  = rcp_fast(1.0f + e1);
    atomicAdd(&corr[b + max(s0, 0)], f0);
    int sB = s0 + 1; if (sB < 32) atomicAdd(&corr[b + sB], f1 - f0);   // sB >= 0 always
    int sC = s0 + 2; if (sC < 32) atomicAdd(&corr[b + sC], 1.0f - f1);
}

// ---- kernel A: graph start offsets from sorted batch ----
__global__ __launch_bounds__(256)
void graph_starts(const int* __restrict__ batch, int* __restrict__ starts) {
    int i = blockIdx.x * 256 + threadIdx.x;
    if (i >= N_NODES) return;
    int b    = batch[i];
    int prev = (i == 0) ? -1 : batch[i - 1];
    for (int g = prev + 1; g <= b; ++g) starts[g] = i;      // unique writer per g
    if (i == N_NODES - 1)
        for (int g = b + 1; g <= NG; ++g) starts[g] = N_NODES;
}

// ---- kernel B: precompute v's bf16 hi/lo tables once (shared by all 3840 main blocks) ----
__global__ __launch_bounds__(256)
void vprep(const float* __restrict__ v,
           unsigned short* __restrict__ vth,   // [32*128] dense
           unsigned short* __restrict__ vtl)
{
    const int tid = threadIdx.x;
    #pragma unroll
    for (int j = 0; j < 4; ++j) {
        int idx4 = tid * 4 + j;                       // 0..1023 float4s
        float4 val = ((const float4*)v)[idx4];
        unsigned short h0,h1,h2,h3,l0,l1,l2,l3;
        split1(val.x, h0, l0); split1(val.y, h1, l1);
        split1(val.z, h2, l2); split1(val.w, h3, l3);
        uint2 hh, ll;
        hh.x = (unsigned)h0 | ((unsigned)h1 << 16); hh.y = (unsigned)h2 | ((unsigned)h3 << 16);
        ll.x = (unsigned)l0 | ((unsigned)l1 << 16); ll.y = (unsigned)l2 | ((unsigned)l3 << 16);
        *(uint2*)&vth[idx4 * 4] = hh;
        *(uint2*)&vtl[idx4 * 4] = ll;
    }
}

// ---- main kernel: one graph-aligned 64-node tile per block, single pass, no global atomics ----
__global__ __launch_bounds__(256, 6)   // 21.6 KB LDS; 84-VGPR budget for x prefetch
void ect_tile(const float* __restrict__ x,
              const float* __restrict__ v,
              const int* __restrict__ starts,
              const unsigned short* __restrict__ vth,
              const unsigned short* __restrict__ vtl,
              float* __restrict__ partials,   // [NG*NTILES][1024]
              float* __restrict__ out,        // fallback target (atomics) when !use_ws
              int use_ws)
{
    __shared__ __align__(16) unsigned short vh[NT * VSTRIDE];  // 8704 B
    __shared__ __align__(16) unsigned short vl[NT * VSTRIDE];  // 8704 B
    __shared__ float corr[NT * HPAD];                          // 4224 B

    const int tid  = threadIdx.x;
    const int t    = blockIdx.x;    // tile within graph
    const int g    = blockIdx.y;    // graph
    const int w    = tid >> 6;
    const int lane = tid & 63;
    const int mrow = lane & 15;
    const int quad = lane >> 4;

    const int start = starts[g];
    const int count = starts[g + 1] - start;
    const int slot  = g * NTILES + t;

    if (t * ATILE >= count) {                    // idle tile: zero-fill ws slot
        if (use_ws) {
            float4 z4 = {0.f, 0.f, 0.f, 0.f};
            *(float4*)&partials[(size_t)slot * 1024 + tid * 4] = z4;
        }
        return;                                  // block-uniform, before any barrier
    }
    const int base   = start + t * ATILE;
    const int nvalid = min(ATILE, count - t * ATILE);  // in [1, 64]

    // ---- prefetch x fragments FIRST: HBM latency hides under v staging ----
    const int gi = min(base + w * 16 + mrow, N_NODES - 1);
    const float* __restrict__ xrow = x + (size_t)gi * NF + quad * 8;
    float4 xa[8];
    #pragma unroll
    for (int slice = 0; slice < 4; ++slice) {
        xa[2 * slice]     = *(const float4*)&xrow[slice * 32];
        xa[2 * slice + 1] = *(const float4*)&xrow[slice * 32 + 4];
    }

    // ---- stage v: plain copy of precomputed hi/lo tables (L2-hot), no math ----
    if (use_ws) {
        #pragma unroll
        for (int j = 0; j < 4; ++j) {
            int idx4 = j * 256 + tid;
            int row  = idx4 >> 5;
            int f4   = idx4 & 31;
            *(uint2*)&vh[row * VSTRIDE + f4 * 4] = *(const uint2*)&vth[idx4 * 4];
            *(uint2*)&vl[row * VSTRIDE + f4 * 4] = *(const uint2*)&vtl[idx4 * 4];
        }
    } else {
        #pragma unroll
        for (int j = 0; j < 4; ++j) {
            int idx4 = j * 256 + tid;
            int row  = idx4 >> 5;
            int f4   = idx4 & 31;
            float4 val = *(const float4*)&v[(size_t)row * NF + f4 * 4];
            unsigned short h0,h1,h2,h3,l0,l1,l2,l3;
            split1(val.x, h0, l0); split1(val.y, h1, l1);
            split1(val.z, h2, l2); split1(val.w, h3, l3);
            uint2 hh, ll;
            hh.x = (unsigned)h0 | ((unsigned)h1 << 16); hh.y = (unsigned)h2 | ((unsigned)h3 << 16);
            ll.x = (unsigned)l0 | ((unsigned)l1 << 16); ll.y = (unsigned)l2 | ((unsigned)l3 << 16);
            *(uint2*)&vh[row * VSTRIDE + f4 * 4] = hh;
            *(uint2*)&vl[row * VSTRIDE + f4 * 4] = ll;
        }
    }
    for (int i = tid; i < NT * HPAD; i += 256) corr[i] = 0.0f;

    // ---- split prefetched x (HW cvt path) while staging drains ----
    bf16x8 ah[4], al[4];
    #pragma unroll
    for (int slice = 0; slice < 4; ++slice)
        split8(xa[2 * slice], xa[2 * slice + 1], ah[slice], al[slice]);
    __syncthreads();   // vh/vl + corr ready

    const int b0base = mrow * VSTRIDE + quad * 8;
    const int b1base = (16 + mrow) * VSTRIDE + quad * 8;

    floatx4 acc0 = {0.f, 0.f, 0.f, 0.f};   // thetas 0..15  (col = mrow)
    floatx4 acc1 = {0.f, 0.f, 0.f, 0.f};   // thetas 16..31
    #pragma unroll
    for (int slice = 0; slice < 4; ++slice) {
        bf16x8 bh0 = *(bf16x8*)&vh[b0base + slice * 32];
        bf16x8 bl0 = *(bf16x8*)&vl[b0base + slice * 32];
        bf16x8 bh1 = *(bf16x8*)&vh[b1base + slice * 32];
        bf16x8 bl1 = *(bf16x8*)&vl[b1base + slice * 32];
        acc0 = __builtin_amdgcn_mfma_f32_16x16x32_bf16(ah[slice], bh0, acc0, 0, 0, 0);
        acc0 = __builtin_amdgcn_mfma_f32_16x16x32_bf16(ah[slice], bl0, acc0, 0, 0, 0);
        acc0 = __builtin_amdgcn_mfma_f32_16x16x32_bf16(al[slice], bh0, acc0, 0, 0, 0);
        acc1 = __builtin_amdgcn_mfma_f32_16x16x32_bf16(ah[slice], bh1, acc1, 0, 0, 0);
        acc1 = __builtin_amdgcn_mfma_f32_16x16x32_bf16(ah[slice], bl1, acc1, 0, 0, 0);
        acc1 = __builtin_amdgcn_mfma_f32_16x16x32_bf16(al[slice], bh1, acc1, 0, 0, 0);
    }
    // C/D layout: col = lane&15 (theta), row = quad*4 + reg (node-in-16-tile)

    const float inv_dlin = 14.090909090909092f; // 31/2.2
    const float Lw       = 10.23848093f;        // SCALE * dlin * log2(e)
    const float dlin     = 2.2f / 31.0f;
    const float L        = 144.26950408889634f; // SCALE * log2(e)
    const float C1       = 8.2777115e-04f;      // 2^-Lw = exp(-SCALE*dlin)

    const int c0base = mrow * HPAD;
    const int c1base = (16 + mrow) * HPAD;

    // ---- dense sweep: 8 positions/thread, difference deposits ----
    float c0 = 0.f, c1 = 0.f;
    const int nloc = w * 16 + quad * 4;
    #pragma unroll
    for (int reg = 0; reg < 4; ++reg) {
        if (nloc + reg < nvalid) {
            {   // theta = mrow
                float z = fmaf(acc0[reg], inv_dlin, 15.5f);   // (h + 1.1)/dlin
                if (z <= -1.0f)      c0 += 1.0f;
                else if (z < 32.0f)  deposit(corr, c0base, z, Lw, C1);
            }
            {   // theta = 16 + mrow
                float z = fmaf(acc1[reg], inv_dlin, 15.5f);
                if (z <= -1.0f)      c1 += 1.0f;
                else if (z < 32.0f)  deposit(corr, c1base, z, Lw, C1);
            }
        }
    }
    if (c0 != 0.f) atomicAdd(&corr[c0base], c0);
    if (c1 != 0.f) atomicAdd(&corr[c1base], c1);
    __syncthreads();

    // ---- inclusive prefix-scan each theta row in place -> sigmoid partial sums ----
    {
        const int grp = tid >> 5;   // 8 groups x 32 lanes; group handles rows grp+8i
        const int sc  = tid & 31;
        for (int row = grp; row < NT; row += 8) {
            float val = corr[row * HPAD + sc];
            #pragma unroll
            for (int d = 1; d < 32; d <<= 1) {
                float nbr = __shfl_up(val, d, 32);
                if (sc >= d) val += nbr;
            }
            corr[row * HPAD + sc] = val;
        }
    }
    __syncthreads();

    // ---- flush: thread owns out-flat indices 4*tid..4*tid+3 (s = tid>>3, ft = (tid&7)*4+j) ----
    const float cnt  = (float)nvalid;
    const int   s    = tid >> 3;
    const int   ft0  = (tid & 7) * 4;
    const float lin_s = -1.1f + (float)s * dlin;
    const float cs    = rcp_fast(1.0f + __builtin_amdgcn_exp2f(L * (1.1f - lin_s)));
    float4 r;
    r.x = corr[(ft0 + 0) * HPAD + s] - cnt * cs;
    r.y = corr[(ft0 + 1) * HPAD + s] - cnt * cs;
    r.z = corr[(ft0 + 2) * HPAD + s] - cnt * cs;
    r.w = corr[(ft0 + 3) * HPAD + s] - cnt * cs;
    if (use_ws) {
        *(float4*)&partials[(size_t)slot * 1024 + tid * 4] = r;   // private slot, coalesced
    } else {
        float* o = out + (size_t)g * (NS * NT) + tid * 4;
        atomicAdd(&o[0], r.x); atomicAdd(&o[1], r.y);
        atomicAdd(&o[2], r.z); atomicAdd(&o[3], r.w);
    }
}

// ---- reduce: out[g][:] = sum over tiles of partials[g][t][:] ----
__global__ __launch_bounds__(256)
void reduce_partials(const float* __restrict__ partials, float* __restrict__ out) {
    const int g   = blockIdx.x;
    const int tid = threadIdx.x;
    const float4* p4 = (const float4*)partials;
    float4 acc = {0.f, 0.f, 0.f, 0.f};
    #pragma unroll
    for (int t = 0; t < NTILES; ++t) {
        float4 v = p4[(size_t)(g * NTILES + t) * 256 + tid];
        acc.x += v.x; acc.y += v.y; acc.z += v.z; acc.w += v.w;
    }
    ((float4*)out)[(size_t)g * 256 + tid] = acc;
}

extern "C" void kernel_launch(void* const* d_in, const int* in_sizes, int n_in,
                              void* d_out, int out_size, void* d_ws, size_t ws_size,
                              hipStream_t stream) {
    const float* x     = (const float*)d_in[0];
    const int*   batch = (const int*)d_in[1];
    const float* v     = (const float*)d_in[3];
    float*       out   = (float*)d_out;

    int*            starts   = (int*)d_ws;                          //   516 B
    unsigned short* vth      = (unsigned short*)((char*)d_ws + 1024);        // 8 KB
    unsigned short* vtl      = (unsigned short*)((char*)d_ws + 1024 + 8192); // 8 KB
    float*          partials = (float*)((char*)d_ws + 1024 + 16384);
    const size_t need = 1024 + 16384 + (size_t)NG * NTILES * 1024 * sizeof(float); // ~15.7 MB
    const int use_ws  = (ws_size >= need) ? 1 : 0;

    hipMemsetAsync(d_out, 0, (size_t)out_size * sizeof(float), stream);
    graph_starts<<<dim3((N_NODES + 255) / 256), dim3(256), 0, stream>>>(batch, starts);
    if (use_ws)
        vprep<<<dim3(1), dim3(256), 0, stream>>>(v, vth, vtl);
    ect_tile<<<dim3(NTILES, NG), dim3(256), 0, stream>>>(x, v, starts, vth, vtl,
                                                         partials, out, use_ws);
    if (use_ws)
        reduce_partials<<<dim3(NG), dim3(256), 0, stream>>>(partials, out);
}